// Round 9
// baseline (279.594 us; speedup 1.0000x reference)
//
#include <hip/hip_runtime.h>
#include <hip/hip_bf16.h>
#include <math.h>

#define N_PTS 8192
#define QPW 4                 // queries per wave
#define WPB 4                 // waves per block
#define QPB (QPW * WPB)       // 16 queries per block
#define BLKS_PER_PASS (N_PTS / QPB)   // 512

// F_CHAMFER*ALPHA0 = 0.02, F_CURVATURE*ALPHA0 = 0.006, F_SMOOTH*ALPHA0 = 0.01
#define W_CHAM 0.02f
#define W_CURV 0.006f
#define W_SMOO 0.01f

#define BIGF 1e30f

// ---- wave-uniform sorted insert (fallback path only) ----
template <int K>
__device__ __forceinline__ void uinsert(float d, int idx, float (&bd)[K], int (&bi)[K]) {
    bd[K - 1] = d; bi[K - 1] = idx;
#pragma unroll
    for (int s = K - 1; s > 0; --s) {
        bool sw = bd[s] < bd[s - 1];
        float td = sw ? bd[s - 1] : bd[s];
        bd[s - 1] = sw ? bd[s] : bd[s - 1];
        bd[s] = td;
        int ti = sw ? bi[s - 1] : bi[s];
        bi[s - 1] = sw ? bi[s] : bi[s - 1];
        bi[s] = ti;
    }
}

// ---- merge 64 per-lane sorted lists {(m1,i1),(m2,i2),(m3,-)} -> global top-K ----
template <int K>
__device__ __forceinline__ void merge_pop(float m1, float m2, float m3, int i1, int i2,
                                          float (&bd)[K], int (&bi)[K], int lane) {
    float h0 = m1, h1 = m2, h2 = m3;
    int   j0 = i1, j1 = i2;
#pragma unroll
    for (int r = 0; r < K; ++r) {
        float bv = h0;
#pragma unroll
        for (int off = 1; off < 64; off <<= 1) bv = fminf(bv, __shfl_xor(bv, off));
        unsigned long long eq = __ballot(h0 == bv);
        int wl = (int)__builtin_ctzll(eq);
        bd[r] = bv; bi[r] = __shfl(j0, wl);
        if (lane == wl) { h0 = h1; j0 = j1; h1 = h2; j1 = -1; h2 = BIGF; }
    }
}

// ---- exact fixed-tau rescan for one query (shifted-distance domain) ----
template <int K>
__device__ void tau_rescan(const float4* __restrict__ cand,
                           float qx, float qy, float qz, float tau,
                           float (&bd)[K], int (&bi)[K], int lane) {
#pragma unroll
    for (int r = 0; r < K; ++r) { bd[r] = BIGF; bi[r] = 0; }
    const float4* cp = cand + lane;
    for (int it = 0; it < N_PTS / 64; ++it) {
        float4 p = cp[it * 64];
        float dot = fmaf(p.x, qx, fmaf(p.y, qy, p.z * qz));
        float d = fmaf(-2.f, dot, p.w);
        unsigned long long m = __ballot(d <= tau);
        while (m) {
            int b = __builtin_ctzll(m);
            m &= m - 1;
            float dv = __shfl(d, b);
            if (dv < bd[K - 1]) uinsert<K>(dv, it * 64 + b, bd, bi);
        }
    }
}

// ---- branchless Q-query scan: per-lane top-2 (indexed) + m3 certificate ----
// cand: float4 (x,y,z,|p|^2). Shifted domain: d' = |p|^2 - 2 p.q via 3 fma
// (nq* = -2q*). Top-3 values via med3/min (3 ops); indices via 2 cmp + 3 sel.
template <int Q>
__device__ __forceinline__ void scanq(const float4* __restrict__ cand,
                                      const float (&nqx)[Q], const float (&nqy)[Q],
                                      const float (&nqz)[Q],
                                      float (&m1)[Q], float (&m2)[Q], float (&m3)[Q],
                                      int (&i1)[Q], int (&i2)[Q], int lane) {
#pragma unroll
    for (int qi = 0; qi < Q; ++qi) { m1[qi] = BIGF; m2[qi] = BIGF; m3[qi] = BIGF; i1[qi] = 0; i2[qi] = 0; }
    const float4* cp = cand + lane;
#pragma unroll 4
    for (int it = 0; it < N_PTS / 64; ++it) {
        float4 p = cp[it * 64];
        const int idx = it * 64 + lane;
#pragma unroll
        for (int qi = 0; qi < Q; ++qi) {
            float d = fmaf(p.x, nqx[qi], fmaf(p.y, nqy[qi], fmaf(p.z, nqz[qi], p.w)));
            bool c1 = d < m1[qi], c2 = d < m2[qi];
            m3[qi] = __builtin_amdgcn_fmed3f(d, m2[qi], m3[qi]);
            m2[qi] = __builtin_amdgcn_fmed3f(d, m1[qi], m2[qi]);
            i2[qi] = c1 ? i1[qi] : (c2 ? idx : i2[qi]);
            m1[qi] = fminf(d, m1[qi]);
            i1[qi] = c1 ? idx : i1[qi];
        }
    }
}

// ---- kernel 0: pack point sets as float4 (xyz,|p|^2), zero accumulators ----
__global__ void prep_kernel(const float* __restrict__ flow, const float* __restrict__ gt,
                            const float* __restrict__ coords,
                            float4* __restrict__ p1q, float4* __restrict__ p2q,
                            float4* __restrict__ wq, float* __restrict__ accs) {
    int i = blockIdx.x * blockDim.x + threadIdx.x;
    if (i < N_PTS) {
        float cx = coords[3 * i + 0], cy = coords[3 * i + 1], cz = coords[3 * i + 2];
        float p2x = cx + gt[3 * i + 0], p2y = cy + gt[3 * i + 1], p2z = cz + gt[3 * i + 2];
        float wx = cx + flow[3 * i + 0], wy = cy + flow[3 * i + 1], wz = cz + flow[3 * i + 2];
        p1q[i] = make_float4(cx, cy, cz, cx * cx + cy * cy + cz * cz);
        p2q[i] = make_float4(p2x, p2y, p2z, p2x * p2x + p2y * p2y + p2z * p2z);
        wq[i]  = make_float4(wx, wy, wz, wx * wx + wy * wy + wz * wz);
    }
    if (i < 8) accs[i] = 0.0f;
}

// ---- fused kernel, 4 roles:
//  0: curv2 (pc2 self-kNN k=10 + curvature epilogue)
//  1: pc1 self-kNN k=10 -> moved_curv + smoothness
//  2: reverse chamfer (min over warp for each pc2 point)
//  3: cross scan: kNN(warp->pc2, 5), store (dist,idx) to ws for the epilogue
__global__ __launch_bounds__(256) void fused4_kernel(const float4* __restrict__ p1q,
                                                     const float4* __restrict__ p2q,
                                                     const float4* __restrict__ wq,
                                                     const float* __restrict__ flow,
                                                     const int* __restrict__ ksm_p,
                                                     float* __restrict__ curv2,
                                                     float* __restrict__ mcurv,
                                                     float* __restrict__ crossd,
                                                     int* __restrict__ crossi,
                                                     float* __restrict__ accs) {
    const int role = blockIdx.x & 3;          // interleave roles across CUs
    const int blk  = blockIdx.x >> 2;
    const int tid = threadIdx.x, lane = tid & 63, wv = tid >> 6;
    const int q0 = blk * QPB + wv * QPW;

    if (role == 2) {
        // ---- reverse chamfer ----
        __shared__ float pmn[WPB];
        float nqx[QPW], nqy[QPW], nqz[QPW], qw[QPW];
#pragma unroll
        for (int qi = 0; qi < QPW; ++qi) {
            float4 t = p2q[q0 + qi];
            nqx[qi] = -2.f * t.x; nqy[qi] = -2.f * t.y; nqz[qi] = -2.f * t.z; qw[qi] = t.w;
        }
        float mn[QPW];
#pragma unroll
        for (int qi = 0; qi < QPW; ++qi) mn[qi] = BIGF;
        const float4* cp = wq + lane;
#pragma unroll 4
        for (int it = 0; it < N_PTS / 64; ++it) {
            float4 p = cp[it * 64];
#pragma unroll
            for (int qi = 0; qi < QPW; ++qi) {
                float d = fmaf(p.x, nqx[qi], fmaf(p.y, nqy[qi], fmaf(p.z, nqz[qi], p.w)));
                mn[qi] = fminf(mn[qi], d);
            }
        }
        float s = 0.f;
#pragma unroll
        for (int qi = 0; qi < QPW; ++qi) {
            float b = mn[qi];
#pragma unroll
            for (int off = 1; off < 64; off <<= 1) b = fminf(b, __shfl_xor(b, off));
            s += b + qw[qi];  // unshift
        }
        if (lane == 0) pmn[wv] = s;
        __syncthreads();
        if (tid == 0) atomicAdd(&accs[1], pmn[0] + pmn[1] + pmn[2] + pmn[3]);
        return;
    }

    // roles 0/1/3: top-K scan
    const float4* qsrc = (role == 0) ? p2q : (role == 1) ? p1q : wq;
    const float4* cand = (role == 1) ? p1q : p2q;
    float nqx[QPW], nqy[QPW], nqz[QPW], qx[QPW], qy[QPW], qz[QPW], qw[QPW];
#pragma unroll
    for (int qi = 0; qi < QPW; ++qi) {
        float4 t = qsrc[q0 + qi];
        qx[qi] = t.x; qy[qi] = t.y; qz[qi] = t.z; qw[qi] = t.w;
        nqx[qi] = -2.f * t.x; nqy[qi] = -2.f * t.y; nqz[qi] = -2.f * t.z;
    }
    float m1[QPW], m2[QPW], m3[QPW]; int i1[QPW], i2[QPW];
    scanq<QPW>(cand, nqx, nqy, nqz, m1, m2, m3, i1, i2, lane);

    if (role == 3) {
        // ---- cross scan: store top-5 (unshifted dist, idx) ----
        constexpr int K = 5;
#pragma unroll
        for (int qi = 0; qi < QPW; ++qi) {
            float bd[K]; int bi[K];
            merge_pop<K>(m1[qi], m2[qi], m3[qi], i1[qi], i2[qi], bd, bi, lane);
            if (__ballot(m3[qi] <= bd[K - 1]) != 0ull)
                tau_rescan<K>(p2q, qx[qi], qy[qi], qz[qi], bd[K - 1], bd, bi, lane);
            const int q = q0 + qi;
            if (lane < K) {
                float dv; int iv;
#pragma unroll
                for (int r = 0; r < K; ++r) { if (lane == r) { dv = bd[r]; iv = bi[r]; } }
                crossd[lane * N_PTS + q] = dv + qw[qi];  // true sq distance
                crossi[lane * N_PTS + q] = iv;
            }
        }
        return;
    }

    constexpr int K = 10;
    if (role == 0) {
        // ---- curvature of pc2 ----
#pragma unroll
        for (int qi = 0; qi < QPW; ++qi) {
            float bd[K]; int bi[K];
            merge_pop<K>(m1[qi], m2[qi], m3[qi], i1[qi], i2[qi], bd, bi, lane);
            if (__ballot(m3[qi] <= bd[K - 1]) != 0ull)
                tau_rescan<K>(p2q, qx[qi], qy[qi], qz[qi], bd[K - 1], bd, bi, lane);
            float ax = 0.f, ay = 0.f, az = 0.f;
#pragma unroll
            for (int r = 0; r < K; ++r) { float4 nb = p2q[bi[r]]; ax += nb.x; ay += nb.y; az += nb.z; }
            if (lane == 0) {
                const int q = q0 + qi;
                curv2[q * 3 + 0] = (ax - 10.f * qx[qi]) * (1.f / 9.f);
                curv2[q * 3 + 1] = (ay - 10.f * qy[qi]) * (1.f / 9.f);
                curv2[q * 3 + 2] = (az - 10.f * qz[qi]) * (1.f / 9.f);
            }
        }
    } else {
        // ---- pc1 self-kNN -> moved_curv + smoothness ----
        __shared__ float psm[WPB];
        const int ksm = ksm_p[0];  // 9
        float smsum = 0.f;
#pragma unroll
        for (int qi = 0; qi < QPW; ++qi) {
            float bd[K]; int bi[K];
            merge_pop<K>(m1[qi], m2[qi], m3[qi], i1[qi], i2[qi], bd, bi, lane);
            if (__ballot(m3[qi] <= bd[K - 1]) != 0ull)
                tau_rescan<K>(p1q, qx[qi], qy[qi], qz[qi], bd[K - 1], bd, bi, lane);
            const int q = q0 + qi;
            float4 wqp = wq[q];
            const float fqx = flow[q * 3 + 0], fqy = flow[q * 3 + 1], fqz = flow[q * 3 + 2];
            float ax = 0.f, ay = 0.f, az = 0.f, sm = 0.f;
#pragma unroll
            for (int r = 0; r < K; ++r) {
                float4 nb = wq[bi[r]];
                ax += nb.x; ay += nb.y; az += nb.z;
                if (r < ksm) {
                    float dx = flow[bi[r] * 3 + 0] - fqx;
                    float dy = flow[bi[r] * 3 + 1] - fqy;
                    float dz = flow[bi[r] * 3 + 2] - fqz;
                    float sq = dx * dx + dy * dy + dz * dz;
                    sm += (sq == 0.f) ? 0.f : sqrtf(sq);
                }
            }
            smsum += sm * 0.125f;  // /8.0 hard-coded in reference
            if (lane == 0) {
                mcurv[q * 3 + 0] = (ax - 10.f * wqp.x) * (1.f / 9.f);
                mcurv[q * 3 + 1] = (ay - 10.f * wqp.y) * (1.f / 9.f);
                mcurv[q * 3 + 2] = (az - 10.f * wqp.z) * (1.f / 9.f);
            }
        }
        if (lane == 0) psm[wv] = smsum;
        __syncthreads();
        if (tid == 0) atomicAdd(&accs[2], psm[0] + psm[1] + psm[2] + psm[3]);
    }
}

// ---- cross epilogue: thread-per-query IDW interp + chamfer1/curv sums ----
__global__ __launch_bounds__(256) void epi_kernel(const float* __restrict__ crossd,
                                                  const int* __restrict__ crossi,
                                                  const float* __restrict__ curv2,
                                                  const float* __restrict__ mcurv,
                                                  float* __restrict__ accs) {
    __shared__ float pd1[WPB], pcv[WPB];
    const int tid = threadIdx.x, lane = tid & 63, wv = tid >> 6;
    const int q = blockIdx.x * 256 + tid;
    constexpr int K = 5;
    float bd[K]; int bi[K];
#pragma unroll
    for (int r = 0; r < K; ++r) { bd[r] = crossd[r * N_PTS + q]; bi[r] = crossi[r * N_PTS + q]; }
    float w[K], wsum = 0.f;
#pragma unroll
    for (int r = 0; r < K; ++r) { w[r] = 1.f / (bd[r] + 1e-8f); wsum += w[r]; }
    float ix = 0.f, iy = 0.f, iz = 0.f;
#pragma unroll
    for (int r = 0; r < K; ++r) {
        float ww = w[r] / wsum;
        ix += ww * curv2[bi[r] * 3 + 0];
        iy += ww * curv2[bi[r] * 3 + 1];
        iz += ww * curv2[bi[r] * 3 + 2];
    }
    float dx = ix - mcurv[q * 3 + 0];
    float dy = iy - mcurv[q * 3 + 1];
    float dz = iz - mcurv[q * 3 + 2];
    float d1 = bd[0];
    float cv = dx * dx + dy * dy + dz * dz;
#pragma unroll
    for (int off = 1; off < 64; off <<= 1) {
        d1 += __shfl_xor(d1, off);
        cv += __shfl_xor(cv, off);
    }
    if (lane == 0) { pd1[wv] = d1; pcv[wv] = cv; }
    __syncthreads();
    if (tid == 0) {
        atomicAdd(&accs[0], pd1[0] + pd1[1] + pd1[2] + pd1[3]);
        atomicAdd(&accs[3], pcv[0] + pcv[1] + pcv[2] + pcv[3]);
    }
}

// ---- finalize ----
__global__ void fin_kernel(const float* __restrict__ accs, float* __restrict__ out) {
    if (threadIdx.x == 0 && blockIdx.x == 0)
        out[0] = W_CHAM * (accs[0] + accs[1]) + W_CURV * accs[3] + W_SMOO * accs[2];
}

extern "C" void kernel_launch(void* const* d_in, const int* in_sizes, int n_in,
                              void* d_out, int out_size, void* d_ws, size_t ws_size,
                              hipStream_t stream) {
    const float* flow   = (const float*)d_in[0];  // registration_pred (1,N,3)
    const float* gt     = (const float*)d_in[1];  // registration_gt   (1,N,3)
    const float* coords = (const float*)d_in[2];  // (N,3)
    const int*   ksm    = (const int*)d_in[3];    // smoothness_k (=9)

    float4* p1q   = (float4*)d_ws;           // N float4 (xyz,|p|^2)
    float4* p2q   = p1q + N_PTS;
    float4* wq    = p2q + N_PTS;
    float*  curv2 = (float*)(wq + N_PTS);    // 3N
    float*  mcurv = curv2 + 3 * N_PTS;       // 3N
    float*  crossd = mcurv + 3 * N_PTS;      // 5N
    int*    crossi = (int*)(crossd + 5 * N_PTS);  // 5N
    float*  accs  = (float*)(crossi + 5 * N_PTS); // 8
    float*  out   = (float*)d_out;

    prep_kernel<<<(N_PTS + 255) / 256, 256, 0, stream>>>(flow, gt, coords, p1q, p2q, wq, accs);
    fused4_kernel<<<4 * BLKS_PER_PASS, 256, 0, stream>>>(p1q, p2q, wq, flow, ksm,
                                                         curv2, mcurv, crossd, crossi, accs);
    epi_kernel<<<N_PTS / 256, 256, 0, stream>>>(crossd, crossi, curv2, mcurv, accs);
    fin_kernel<<<1, 64, 0, stream>>>(accs, out);
}

// Round 10
// 220.677 us; speedup vs baseline: 1.2670x; 1.2670x over previous
//
#include <hip/hip_runtime.h>
#include <hip/hip_bf16.h>
#include <math.h>

#define N_PTS 8192
#define QPW 4                 // queries per wave
#define WPB 4                 // waves per block
#define QPB (QPW * WPB)       // 16 queries per block
#define BLKS_PER_PASS (N_PTS / QPB)   // 512

// F_CHAMFER*ALPHA0 = 0.02, F_CURVATURE*ALPHA0 = 0.006, F_SMOOTH*ALPHA0 = 0.01
#define W_CHAM 0.02f
#define W_CURV 0.006f
#define W_SMOO 0.01f

#define BIGF 1e30f

// ---- wave-uniform sorted insert (fallback path only) ----
template <int K>
__device__ __forceinline__ void uinsert(float d, int idx, float (&bd)[K], int (&bi)[K]) {
    bd[K - 1] = d; bi[K - 1] = idx;
#pragma unroll
    for (int s = K - 1; s > 0; --s) {
        bool sw = bd[s] < bd[s - 1];
        float td = sw ? bd[s - 1] : bd[s];
        bd[s - 1] = sw ? bd[s] : bd[s - 1];
        bd[s] = td;
        int ti = sw ? bi[s - 1] : bi[s];
        bi[s - 1] = sw ? bi[s] : bi[s - 1];
        bi[s] = ti;
    }
}

// ---- merge 64 per-lane sorted lists {(m1,i1),(m2,i2),(m3,-)} -> global top-K ----
template <int K>
__device__ __forceinline__ void merge_pop(float m1, float m2, float m3, int i1, int i2,
                                          float (&bd)[K], int (&bi)[K], int lane) {
    float h0 = m1, h1 = m2, h2 = m3;
    int   j0 = i1, j1 = i2;
#pragma unroll
    for (int r = 0; r < K; ++r) {
        float bv = h0;
#pragma unroll
        for (int off = 1; off < 64; off <<= 1) bv = fminf(bv, __shfl_xor(bv, off));
        unsigned long long eq = __ballot(h0 == bv);
        int wl = (int)__builtin_ctzll(eq);
        bd[r] = bv; bi[r] = __shfl(j0, wl);
        if (lane == wl) { h0 = h1; j0 = j1; h1 = h2; j1 = -1; h2 = BIGF; }
    }
}

// ---- exact fixed-tau rescan for one query (shifted-distance domain) ----
template <int K>
__device__ void tau_rescan(const float4* __restrict__ cand,
                           float qx, float qy, float qz, float tau,
                           float (&bd)[K], int (&bi)[K], int lane) {
#pragma unroll
    for (int r = 0; r < K; ++r) { bd[r] = BIGF; bi[r] = 0; }
    const float4* cp = cand + lane;
    for (int it = 0; it < N_PTS / 64; ++it) {
        float4 p = cp[it * 64];
        float dot = fmaf(p.x, qx, fmaf(p.y, qy, p.z * qz));
        float d = fmaf(-2.f, dot, p.w);
        unsigned long long m = __ballot(d <= tau);
        while (m) {
            int b = __builtin_ctzll(m);
            m &= m - 1;
            float dv = __shfl(d, b);
            if (dv < bd[K - 1]) uinsert<K>(dv, it * 64 + b, bd, bi);
        }
    }
}

// ---- branchless Q-query scan: per-lane top-2 (indexed) + m3 certificate ----
// cand: float4 (x,y,z,|p|^2). Shifted domain: d' = |p|^2 - 2 p.q via 3 fma
// (nq* = -2q*). Top-3 values via med3/min (3 ops); indices via 2 cmp + 3 sel.
template <int Q>
__device__ __forceinline__ void scanq(const float4* __restrict__ cand,
                                      const float (&nqx)[Q], const float (&nqy)[Q],
                                      const float (&nqz)[Q],
                                      float (&m1)[Q], float (&m2)[Q], float (&m3)[Q],
                                      int (&i1)[Q], int (&i2)[Q], int lane) {
#pragma unroll
    for (int qi = 0; qi < Q; ++qi) { m1[qi] = BIGF; m2[qi] = BIGF; m3[qi] = BIGF; i1[qi] = 0; i2[qi] = 0; }
    const float4* cp = cand + lane;
#pragma unroll 4
    for (int it = 0; it < N_PTS / 64; ++it) {
        float4 p = cp[it * 64];
        const int idx = it * 64 + lane;
#pragma unroll
        for (int qi = 0; qi < Q; ++qi) {
            float d = fmaf(p.x, nqx[qi], fmaf(p.y, nqy[qi], fmaf(p.z, nqz[qi], p.w)));
            bool c1 = d < m1[qi], c2 = d < m2[qi];
            m3[qi] = __builtin_amdgcn_fmed3f(d, m2[qi], m3[qi]);
            m2[qi] = __builtin_amdgcn_fmed3f(d, m1[qi], m2[qi]);
            i2[qi] = c1 ? i1[qi] : (c2 ? idx : i2[qi]);
            m1[qi] = fminf(d, m1[qi]);
            i1[qi] = c1 ? idx : i1[qi];
        }
    }
}

// ---- kernel 0: pack point sets as float4 (xyz,|p|^2), zero accumulators ----
__global__ void prep_kernel(const float* __restrict__ flow, const float* __restrict__ gt,
                            const float* __restrict__ coords,
                            float4* __restrict__ p1q, float4* __restrict__ p2q,
                            float4* __restrict__ wq, float* __restrict__ accs) {
    int i = blockIdx.x * blockDim.x + threadIdx.x;
    if (i < N_PTS) {
        float cx = coords[3 * i + 0], cy = coords[3 * i + 1], cz = coords[3 * i + 2];
        float p2x = cx + gt[3 * i + 0], p2y = cy + gt[3 * i + 1], p2z = cz + gt[3 * i + 2];
        float wx = cx + flow[3 * i + 0], wy = cy + flow[3 * i + 1], wz = cz + flow[3 * i + 2];
        p1q[i] = make_float4(cx, cy, cz, cx * cx + cy * cy + cz * cz);
        p2q[i] = make_float4(p2x, p2y, p2z, p2x * p2x + p2y * p2y + p2z * p2z);
        wq[i]  = make_float4(wx, wy, wz, wx * wx + wy * wy + wz * wz);
    }
    if (i < 8) accs[i] = 0.0f;
}

// ---- fused kernel, 4 roles (contiguous mapping: role spreads over all XCDs):
//  0: curv2 (pc2 self-kNN k=10 + curvature epilogue)
//  1: pc1 self-kNN k=10 -> moved_curv + smoothness
//  2: reverse chamfer (min over warp for each pc2 point)
//  3: cross scan: kNN(warp->pc2, 5), store (dist,idx) to ws for the epilogue
__global__ __launch_bounds__(256) void fused4_kernel(const float4* __restrict__ p1q,
                                                     const float4* __restrict__ p2q,
                                                     const float4* __restrict__ wq,
                                                     const float* __restrict__ flow,
                                                     const int* __restrict__ ksm_p,
                                                     float* __restrict__ curv2,
                                                     float* __restrict__ mcurv,
                                                     float* __restrict__ crossd,
                                                     int* __restrict__ crossi,
                                                     float* __restrict__ accs) {
    const int role = blockIdx.x / BLKS_PER_PASS;   // contiguous: every XCD sees every role
    const int blk  = blockIdx.x % BLKS_PER_PASS;
    const int tid = threadIdx.x, lane = tid & 63, wv = tid >> 6;
    const int q0 = blk * QPB + wv * QPW;

    if (role == 2) {
        // ---- reverse chamfer ----
        __shared__ float pmn[WPB];
        float nqx[QPW], nqy[QPW], nqz[QPW], qw[QPW];
#pragma unroll
        for (int qi = 0; qi < QPW; ++qi) {
            float4 t = p2q[q0 + qi];
            nqx[qi] = -2.f * t.x; nqy[qi] = -2.f * t.y; nqz[qi] = -2.f * t.z; qw[qi] = t.w;
        }
        float mn[QPW];
#pragma unroll
        for (int qi = 0; qi < QPW; ++qi) mn[qi] = BIGF;
        const float4* cp = wq + lane;
#pragma unroll 4
        for (int it = 0; it < N_PTS / 64; ++it) {
            float4 p = cp[it * 64];
#pragma unroll
            for (int qi = 0; qi < QPW; ++qi) {
                float d = fmaf(p.x, nqx[qi], fmaf(p.y, nqy[qi], fmaf(p.z, nqz[qi], p.w)));
                mn[qi] = fminf(mn[qi], d);
            }
        }
        float s = 0.f;
#pragma unroll
        for (int qi = 0; qi < QPW; ++qi) {
            float b = mn[qi];
#pragma unroll
            for (int off = 1; off < 64; off <<= 1) b = fminf(b, __shfl_xor(b, off));
            s += b + qw[qi];  // unshift
        }
        if (lane == 0) pmn[wv] = s;
        __syncthreads();
        if (tid == 0) atomicAdd(&accs[1], pmn[0] + pmn[1] + pmn[2] + pmn[3]);
        return;
    }

    // roles 0/1/3: top-K scan
    const float4* qsrc = (role == 0) ? p2q : (role == 1) ? p1q : wq;
    const float4* cand = (role == 1) ? p1q : p2q;
    float nqx[QPW], nqy[QPW], nqz[QPW], qx[QPW], qy[QPW], qz[QPW], qw[QPW];
#pragma unroll
    for (int qi = 0; qi < QPW; ++qi) {
        float4 t = qsrc[q0 + qi];
        qx[qi] = t.x; qy[qi] = t.y; qz[qi] = t.z; qw[qi] = t.w;
        nqx[qi] = -2.f * t.x; nqy[qi] = -2.f * t.y; nqz[qi] = -2.f * t.z;
    }
    float m1[QPW], m2[QPW], m3[QPW]; int i1[QPW], i2[QPW];
    scanq<QPW>(cand, nqx, nqy, nqz, m1, m2, m3, i1, i2, lane);

    if (role == 3) {
        // ---- cross scan: store top-5 (unshifted dist, idx) ----
        constexpr int K = 5;
#pragma unroll
        for (int qi = 0; qi < QPW; ++qi) {
            float bd[K]; int bi[K];
            merge_pop<K>(m1[qi], m2[qi], m3[qi], i1[qi], i2[qi], bd, bi, lane);
            if (__ballot(m3[qi] <= bd[K - 1]) != 0ull)
                tau_rescan<K>(p2q, qx[qi], qy[qi], qz[qi], bd[K - 1], bd, bi, lane);
            const int q = q0 + qi;
            if (lane < K) {
                float dv; int iv;
#pragma unroll
                for (int r = 0; r < K; ++r) { if (lane == r) { dv = bd[r]; iv = bi[r]; } }
                crossd[lane * N_PTS + q] = dv + qw[qi];  // true sq distance
                crossi[lane * N_PTS + q] = iv;
            }
        }
        return;
    }

    constexpr int K = 10;
    if (role == 0) {
        // ---- curvature of pc2 ----
#pragma unroll
        for (int qi = 0; qi < QPW; ++qi) {
            float bd[K]; int bi[K];
            merge_pop<K>(m1[qi], m2[qi], m3[qi], i1[qi], i2[qi], bd, bi, lane);
            if (__ballot(m3[qi] <= bd[K - 1]) != 0ull)
                tau_rescan<K>(p2q, qx[qi], qy[qi], qz[qi], bd[K - 1], bd, bi, lane);
            float ax = 0.f, ay = 0.f, az = 0.f;
#pragma unroll
            for (int r = 0; r < K; ++r) { float4 nb = p2q[bi[r]]; ax += nb.x; ay += nb.y; az += nb.z; }
            if (lane == 0) {
                const int q = q0 + qi;
                curv2[q * 3 + 0] = (ax - 10.f * qx[qi]) * (1.f / 9.f);
                curv2[q * 3 + 1] = (ay - 10.f * qy[qi]) * (1.f / 9.f);
                curv2[q * 3 + 2] = (az - 10.f * qz[qi]) * (1.f / 9.f);
            }
        }
    } else {
        // ---- pc1 self-kNN -> moved_curv + smoothness ----
        __shared__ float psm[WPB];
        const int ksm = ksm_p[0];  // 9
        float smsum = 0.f;
#pragma unroll
        for (int qi = 0; qi < QPW; ++qi) {
            float bd[K]; int bi[K];
            merge_pop<K>(m1[qi], m2[qi], m3[qi], i1[qi], i2[qi], bd, bi, lane);
            if (__ballot(m3[qi] <= bd[K - 1]) != 0ull)
                tau_rescan<K>(p1q, qx[qi], qy[qi], qz[qi], bd[K - 1], bd, bi, lane);
            const int q = q0 + qi;
            float4 wqp = wq[q];
            const float fqx = flow[q * 3 + 0], fqy = flow[q * 3 + 1], fqz = flow[q * 3 + 2];
            float ax = 0.f, ay = 0.f, az = 0.f, sm = 0.f;
#pragma unroll
            for (int r = 0; r < K; ++r) {
                float4 nb = wq[bi[r]];
                ax += nb.x; ay += nb.y; az += nb.z;
                if (r < ksm) {
                    float dx = flow[bi[r] * 3 + 0] - fqx;
                    float dy = flow[bi[r] * 3 + 1] - fqy;
                    float dz = flow[bi[r] * 3 + 2] - fqz;
                    float sq = dx * dx + dy * dy + dz * dz;
                    sm += (sq == 0.f) ? 0.f : sqrtf(sq);
                }
            }
            smsum += sm * 0.125f;  // /8.0 hard-coded in reference
            if (lane == 0) {
                mcurv[q * 3 + 0] = (ax - 10.f * wqp.x) * (1.f / 9.f);
                mcurv[q * 3 + 1] = (ay - 10.f * wqp.y) * (1.f / 9.f);
                mcurv[q * 3 + 2] = (az - 10.f * wqp.z) * (1.f / 9.f);
            }
        }
        if (lane == 0) psm[wv] = smsum;
        __syncthreads();
        if (tid == 0) atomicAdd(&accs[2], psm[0] + psm[1] + psm[2] + psm[3]);
    }
}

// ---- cross epilogue: thread-per-query IDW interp + chamfer1/curv sums ----
__global__ __launch_bounds__(256) void epi_kernel(const float* __restrict__ crossd,
                                                  const int* __restrict__ crossi,
                                                  const float* __restrict__ curv2,
                                                  const float* __restrict__ mcurv,
                                                  float* __restrict__ accs) {
    __shared__ float pd1[WPB], pcv[WPB];
    const int tid = threadIdx.x, lane = tid & 63, wv = tid >> 6;
    const int q = blockIdx.x * 256 + tid;
    constexpr int K = 5;
    float bd[K]; int bi[K];
#pragma unroll
    for (int r = 0; r < K; ++r) { bd[r] = crossd[r * N_PTS + q]; bi[r] = crossi[r * N_PTS + q]; }
    float w[K], wsum = 0.f;
#pragma unroll
    for (int r = 0; r < K; ++r) { w[r] = 1.f / (bd[r] + 1e-8f); wsum += w[r]; }
    float ix = 0.f, iy = 0.f, iz = 0.f;
#pragma unroll
    for (int r = 0; r < K; ++r) {
        float ww = w[r] / wsum;
        ix += ww * curv2[bi[r] * 3 + 0];
        iy += ww * curv2[bi[r] * 3 + 1];
        iz += ww * curv2[bi[r] * 3 + 2];
    }
    float dx = ix - mcurv[q * 3 + 0];
    float dy = iy - mcurv[q * 3 + 1];
    float dz = iz - mcurv[q * 3 + 2];
    float d1 = bd[0];
    float cv = dx * dx + dy * dy + dz * dz;
#pragma unroll
    for (int off = 1; off < 64; off <<= 1) {
        d1 += __shfl_xor(d1, off);
        cv += __shfl_xor(cv, off);
    }
    if (lane == 0) { pd1[wv] = d1; pcv[wv] = cv; }
    __syncthreads();
    if (tid == 0) {
        atomicAdd(&accs[0], pd1[0] + pd1[1] + pd1[2] + pd1[3]);
        atomicAdd(&accs[3], pcv[0] + pcv[1] + pcv[2] + pcv[3]);
    }
}

// ---- finalize ----
__global__ void fin_kernel(const float* __restrict__ accs, float* __restrict__ out) {
    if (threadIdx.x == 0 && blockIdx.x == 0)
        out[0] = W_CHAM * (accs[0] + accs[1]) + W_CURV * accs[3] + W_SMOO * accs[2];
}

extern "C" void kernel_launch(void* const* d_in, const int* in_sizes, int n_in,
                              void* d_out, int out_size, void* d_ws, size_t ws_size,
                              hipStream_t stream) {
    const float* flow   = (const float*)d_in[0];  // registration_pred (1,N,3)
    const float* gt     = (const float*)d_in[1];  // registration_gt   (1,N,3)
    const float* coords = (const float*)d_in[2];  // (N,3)
    const int*   ksm    = (const int*)d_in[3];    // smoothness_k (=9)

    float4* p1q   = (float4*)d_ws;           // N float4 (xyz,|p|^2)
    float4* p2q   = p1q + N_PTS;
    float4* wq    = p2q + N_PTS;
    float*  curv2 = (float*)(wq + N_PTS);    // 3N
    float*  mcurv = curv2 + 3 * N_PTS;       // 3N
    float*  crossd = mcurv + 3 * N_PTS;      // 5N
    int*    crossi = (int*)(crossd + 5 * N_PTS);  // 5N
    float*  accs  = (float*)(crossi + 5 * N_PTS); // 8
    float*  out   = (float*)d_out;

    prep_kernel<<<(N_PTS + 255) / 256, 256, 0, stream>>>(flow, gt, coords, p1q, p2q, wq, accs);
    fused4_kernel<<<4 * BLKS_PER_PASS, 256, 0, stream>>>(p1q, p2q, wq, flow, ksm,
                                                         curv2, mcurv, crossd, crossi, accs);
    epi_kernel<<<N_PTS / 256, 256, 0, stream>>>(crossd, crossi, curv2, mcurv, accs);
    fin_kernel<<<1, 64, 0, stream>>>(accs, out);
}